// Round 1
// baseline (527.673 us; speedup 1.0000x reference)
//
#include <hip/hip_runtime.h>
#include <hip/hip_bf16.h>

#define S 2048
#define D 1024
#define NE 8
#define HF 4096
#define HH 8192
#define BM 64
#define BN 64
#define BK 32
#define LDT 40  // padded LDS tile row length (elements) -> 80B stride, 16B aligned

typedef __attribute__((ext_vector_type(8))) __bf16 bf16x8;
typedef __attribute__((ext_vector_type(4))) float f32x4;

__device__ __forceinline__ unsigned bf16b(float f) {
  unsigned b = __float_as_uint(f);
  return (b + 0x7fffu + ((b >> 16) & 1u)) >> 16;  // RNE fp32->bf16 (finite inputs)
}
__device__ __forceinline__ unsigned pk2(float lo, float hi) {
  return bf16b(lo) | (bf16b(hi) << 16);
}

// ---------------- gating: logits, top-2, softmax over the 2 ----------------
__global__ void gate_kernel(const float* __restrict__ x, const float* __restrict__ gw,
                            const float* __restrict__ gb, int* __restrict__ counts,
                            int* __restrict__ mi0, int* __restrict__ mi1,
                            float* __restrict__ mw0, float* __restrict__ mw1) {
  const int t = blockIdx.x;
  const int l = threadIdx.x;
  const float* xr = x + (size_t)t * D;
  float acc[NE];
#pragma unroll
  for (int e = 0; e < NE; ++e) acc[e] = 0.f;
  for (int d = l; d < D; d += 64) {
    float xv = xr[d];
    const float* g = gw + (size_t)d * NE;
#pragma unroll
    for (int e = 0; e < NE; ++e) acc[e] += xv * g[e];
  }
#pragma unroll
  for (int e = 0; e < NE; ++e) {
    float v = acc[e];
#pragma unroll
    for (int off = 32; off > 0; off >>= 1) v += __shfl_xor(v, off);
    acc[e] = v;
  }
  if (l == 0) {
    float lg[NE];
#pragma unroll
    for (int e = 0; e < NE; ++e) lg[e] = acc[e] + gb[e];
    int i0 = 0; float m0 = lg[0];
#pragma unroll
    for (int e = 1; e < NE; ++e) if (lg[e] > m0) { m0 = lg[e]; i0 = e; }  // strict >: first idx on ties (jax)
    int i1 = -1; float m1 = -3.4e38f;
#pragma unroll
    for (int e = 0; e < NE; ++e) if (e != i0 && lg[e] > m1) { m1 = lg[e]; i1 = e; }
    float p = __expf(m1 - m0);          // <= 1
    float inv = 1.f / (1.f + p);
    mi0[t] = i0; mi1[t] = i1;
    mw0[t] = inv; mw1[t] = p * inv;
    atomicAdd(&counts[i0], 1);
    atomicAdd(&counts[i1], 1);
  }
}

__global__ void scan_kernel(const int* __restrict__ counts, int* __restrict__ basep) {
  if (threadIdx.x == 0) {
    int s = 0;
#pragma unroll
    for (int e = 0; e < NE; ++e) { basep[e] = s; s += counts[e]; }
    basep[NE] = s;
  }
}

__global__ void fill_kernel(const int* __restrict__ mi0, const int* __restrict__ mi1,
                            int* __restrict__ cursor, const int* __restrict__ basep,
                            int* __restrict__ list_tok, int* __restrict__ mr0,
                            int* __restrict__ mr1) {
  int t = blockIdx.x * blockDim.x + threadIdx.x;
  if (t >= S) return;
  int e0 = mi0[t];
  int r0 = basep[e0] + atomicAdd(&cursor[e0], 1);
  list_tok[r0] = t; mr0[t] = r0;
  int e1 = mi1[t];
  int r1 = basep[e1] + atomicAdd(&cursor[e1], 1);
  list_tok[r1] = t; mr1[t] = r1;
}

// -------- GEMM1 + SwiGLU: act[row, jt..jt+63] from both H halves (bf16 out) --------
__global__ __launch_bounds__(256) void gemm1_kernel(
    const float* __restrict__ x, const float* __restrict__ w1,
    const float* __restrict__ b1, const int* __restrict__ counts,
    const int* __restrict__ basep, const int* __restrict__ list_tok,
    ushort* __restrict__ act_buf) {
  const int e = blockIdx.y >> 5;
  const int row0 = (blockIdx.y & 31) * BM;
  const int cnt = counts[e];
  if (row0 >= cnt) return;
  const int jt = blockIdx.x * BN;
  const float* __restrict__ W = w1 + (size_t)e * D * HH;
  const float* __restrict__ bb = b1 + (size_t)e * HH;
  const int gbase = basep[e];

  __shared__ ushort As[BM][LDT];
  __shared__ ushort Bs[2][BN][LDT];  // k-minor (transposed) per half
  __shared__ int toks[BM];

  const int tid = threadIdx.x;
  if (tid < BM) {
    const int slot = row0 + tid;
    toks[tid] = (slot < cnt) ? list_tok[gbase + slot] : 0;
  }
  __syncthreads();

  const int ar = tid >> 2;            // A row 0..63
  const int ac = (tid & 3) * 8;       // A col {0,8,16,24}
  const float* __restrict__ xrow = x + (size_t)toks[ar] * D + ac;
  const int bk2 = (tid >> 4) * 2;     // B k {0..30 even}
  const int bn4 = (tid & 15) * 4;     // B n {0..60}
  const float* __restrict__ Wst = W + (size_t)bk2 * HH + jt + bn4;

  const int wave = tid >> 6;
  const int lane = tid & 63;
  const int wm = (wave >> 1) * 32;
  const int wn = (wave & 1) * 32;
  const int lr = lane & 15;
  const int kg = lane >> 4;

  f32x4 acc[2][2][2] = {};  // [half][mi][ni]

  for (int k0 = 0; k0 < D; k0 += BK) {
    float4 a0 = *(const float4*)(xrow + k0);
    float4 a1 = *(const float4*)(xrow + k0 + 4);
    const float* wp = Wst + (size_t)k0 * HH;
    float4 bx0 = *(const float4*)(wp);
    float4 bx1 = *(const float4*)(wp + HH);
    float4 bg0 = *(const float4*)(wp + HF);
    float4 bg1 = *(const float4*)(wp + HH + HF);
    __syncthreads();
    uint4 aw = { pk2(a0.x, a0.y), pk2(a0.z, a0.w), pk2(a1.x, a1.y), pk2(a1.z, a1.w) };
    *(uint4*)&As[ar][ac] = aw;
    *(unsigned*)&Bs[0][bn4 + 0][bk2] = pk2(bx0.x, bx1.x);
    *(unsigned*)&Bs[0][bn4 + 1][bk2] = pk2(bx0.y, bx1.y);
    *(unsigned*)&Bs[0][bn4 + 2][bk2] = pk2(bx0.z, bx1.z);
    *(unsigned*)&Bs[0][bn4 + 3][bk2] = pk2(bx0.w, bx1.w);
    *(unsigned*)&Bs[1][bn4 + 0][bk2] = pk2(bg0.x, bg1.x);
    *(unsigned*)&Bs[1][bn4 + 1][bk2] = pk2(bg0.y, bg1.y);
    *(unsigned*)&Bs[1][bn4 + 2][bk2] = pk2(bg0.z, bg1.z);
    *(unsigned*)&Bs[1][bn4 + 3][bk2] = pk2(bg0.w, bg1.w);
    __syncthreads();
    bf16x8 af0 = *(const bf16x8*)&As[wm + lr][kg * 8];
    bf16x8 af1 = *(const bf16x8*)&As[wm + 16 + lr][kg * 8];
    bf16x8 bx_0 = *(const bf16x8*)&Bs[0][wn + lr][kg * 8];
    bf16x8 bx_1 = *(const bf16x8*)&Bs[0][wn + 16 + lr][kg * 8];
    bf16x8 bg_0 = *(const bf16x8*)&Bs[1][wn + lr][kg * 8];
    bf16x8 bg_1 = *(const bf16x8*)&Bs[1][wn + 16 + lr][kg * 8];
    acc[0][0][0] = __builtin_amdgcn_mfma_f32_16x16x32_bf16(af0, bx_0, acc[0][0][0], 0, 0, 0);
    acc[0][0][1] = __builtin_amdgcn_mfma_f32_16x16x32_bf16(af0, bx_1, acc[0][0][1], 0, 0, 0);
    acc[0][1][0] = __builtin_amdgcn_mfma_f32_16x16x32_bf16(af1, bx_0, acc[0][1][0], 0, 0, 0);
    acc[0][1][1] = __builtin_amdgcn_mfma_f32_16x16x32_bf16(af1, bx_1, acc[0][1][1], 0, 0, 0);
    acc[1][0][0] = __builtin_amdgcn_mfma_f32_16x16x32_bf16(af0, bg_0, acc[1][0][0], 0, 0, 0);
    acc[1][0][1] = __builtin_amdgcn_mfma_f32_16x16x32_bf16(af0, bg_1, acc[1][0][1], 0, 0, 0);
    acc[1][1][0] = __builtin_amdgcn_mfma_f32_16x16x32_bf16(af1, bg_0, acc[1][1][0], 0, 0, 0);
    acc[1][1][1] = __builtin_amdgcn_mfma_f32_16x16x32_bf16(af1, bg_1, acc[1][1][1], 0, 0, 0);
  }

#pragma unroll
  for (int mi = 0; mi < 2; ++mi)
#pragma unroll
    for (int ni = 0; ni < 2; ++ni) {
      const int c = jt + wn + ni * 16 + lr;   // act col 0..4095
      const float bx = bb[c];
      const float bg = bb[HF + c];
      f32x4 vx = acc[0][mi][ni];
      f32x4 vg = acc[1][mi][ni];
#pragma unroll
      for (int q = 0; q < 4; ++q) {
        const int slot = row0 + wm + mi * 16 + kg * 4 + q;  // C/D: col=lane&15, row=(lane>>4)*4+q
        if (slot < cnt) {
          float xv = vx[q] + bx;
          float g = vg[q] + bg;
          float a = g / (1.f + __expf(-g)) * xv;  // silu(g)*x
          act_buf[(size_t)(gbase + slot) * HF + c] = (ushort)bf16b(a);
        }
      }
    }
}

// -------------------- GEMM2: oe[row, jt..jt+63] = act @ W2[e] --------------------
__global__ __launch_bounds__(256) void gemm2_kernel(
    const ushort* __restrict__ act_buf, const float* __restrict__ w2,
    const int* __restrict__ counts, const int* __restrict__ basep,
    float* __restrict__ oe) {
  const int e = blockIdx.y >> 5;
  const int row0 = (blockIdx.y & 31) * BM;
  const int cnt = counts[e];
  if (row0 >= cnt) return;
  const int jt = blockIdx.x * BN;
  const float* __restrict__ W = w2 + (size_t)e * HF * D;
  const int gbase = basep[e];

  __shared__ ushort As[BM][LDT];
  __shared__ ushort Bs[BN][LDT];

  const int tid = threadIdx.x;
  const int ar = tid >> 2;
  const int ac = (tid & 3) * 8;
  const ushort* __restrict__ arow = act_buf + (size_t)(gbase + row0 + ar) * HF + ac;
  const int bk2 = (tid >> 4) * 2;
  const int bn4 = (tid & 15) * 4;
  const float* __restrict__ Wst = W + (size_t)bk2 * D + jt + bn4;

  const int wave = tid >> 6;
  const int lane = tid & 63;
  const int wm = (wave >> 1) * 32;
  const int wn = (wave & 1) * 32;
  const int lr = lane & 15;
  const int kg = lane >> 4;

  f32x4 acc[2][2] = {};

  for (int k0 = 0; k0 < HF; k0 += BK) {
    uint4 a = *(const uint4*)(arow + k0);    // act already bf16: pure copy
    const float* wp = Wst + (size_t)k0 * D;
    float4 b0 = *(const float4*)(wp);
    float4 b1v = *(const float4*)(wp + D);
    __syncthreads();
    *(uint4*)&As[ar][ac] = a;
    *(unsigned*)&Bs[bn4 + 0][bk2] = pk2(b0.x, b1v.x);
    *(unsigned*)&Bs[bn4 + 1][bk2] = pk2(b0.y, b1v.y);
    *(unsigned*)&Bs[bn4 + 2][bk2] = pk2(b0.z, b1v.z);
    *(unsigned*)&Bs[bn4 + 3][bk2] = pk2(b0.w, b1v.w);
    __syncthreads();
    bf16x8 af0 = *(const bf16x8*)&As[wm + lr][kg * 8];
    bf16x8 af1 = *(const bf16x8*)&As[wm + 16 + lr][kg * 8];
    bf16x8 bf0 = *(const bf16x8*)&Bs[wn + lr][kg * 8];
    bf16x8 bf1 = *(const bf16x8*)&Bs[wn + 16 + lr][kg * 8];
    acc[0][0] = __builtin_amdgcn_mfma_f32_16x16x32_bf16(af0, bf0, acc[0][0], 0, 0, 0);
    acc[0][1] = __builtin_amdgcn_mfma_f32_16x16x32_bf16(af0, bf1, acc[0][1], 0, 0, 0);
    acc[1][0] = __builtin_amdgcn_mfma_f32_16x16x32_bf16(af1, bf0, acc[1][0], 0, 0, 0);
    acc[1][1] = __builtin_amdgcn_mfma_f32_16x16x32_bf16(af1, bf1, acc[1][1], 0, 0, 0);
  }

#pragma unroll
  for (int mi = 0; mi < 2; ++mi)
#pragma unroll
    for (int ni = 0; ni < 2; ++ni) {
      f32x4 v = acc[mi][ni];
#pragma unroll
      for (int q = 0; q < 4; ++q) {
        const int slot = row0 + wm + mi * 16 + kg * 4 + q;
        if (slot < cnt)
          oe[(size_t)(gbase + slot) * D + jt + wn + ni * 16 + lr] = v[q];
      }
    }
}

// ---------------- combine: out[t] = w0*(oe[r0]+b2[e0]) + w1*(oe[r1]+b2[e1]) ----------------
__global__ void combine_kernel(const float* __restrict__ oe,
                               const int* __restrict__ mr0, const int* __restrict__ mr1,
                               const float* __restrict__ mw0, const float* __restrict__ mw1,
                               const int* __restrict__ mi0, const int* __restrict__ mi1,
                               const float* __restrict__ b2, float* __restrict__ out) {
  const int t = blockIdx.x;
  const int l = threadIdx.x;  // 256 threads * float4 = 1024
  const float w0 = mw0[t], w1 = mw1[t];
  const float4* p0 = (const float4*)(oe + (size_t)mr0[t] * D);
  const float4* p1 = (const float4*)(oe + (size_t)mr1[t] * D);
  const float4* c0 = (const float4*)(b2 + (size_t)mi0[t] * D);
  const float4* c1 = (const float4*)(b2 + (size_t)mi1[t] * D);
  float4 A = p0[l], B = p1[l], C = c0[l], E = c1[l];
  float4 r;
  r.x = w0 * (A.x + C.x) + w1 * (B.x + E.x);
  r.y = w0 * (A.y + C.y) + w1 * (B.y + E.y);
  r.z = w0 * (A.z + C.z) + w1 * (B.z + E.z);
  r.w = w0 * (A.w + C.w) + w1 * (B.w + E.w);
  ((float4*)(out + (size_t)t * D))[l] = r;
}

extern "C" void kernel_launch(void* const* d_in, const int* in_sizes, int n_in,
                              void* d_out, int out_size, void* d_ws, size_t ws_size,
                              hipStream_t stream) {
  const float* x  = (const float*)d_in[0];
  const float* gw = (const float*)d_in[1];
  const float* gb = (const float*)d_in[2];
  const float* w1 = (const float*)d_in[3];
  const float* b1 = (const float*)d_in[4];
  const float* w2 = (const float*)d_in[5];
  const float* b2 = (const float*)d_in[6];
  float* out = (float*)d_out;

  char* ws = (char*)d_ws;
  int*   counts   = (int*)(ws + 0);
  int*   cursor   = (int*)(ws + 32);
  int*   basep    = (int*)(ws + 64);
  int*   mi0      = (int*)(ws + 128);
  int*   mi1      = (int*)(ws + 128 + 1 * 8192);
  int*   mr0      = (int*)(ws + 128 + 2 * 8192);
  int*   mr1      = (int*)(ws + 128 + 3 * 8192);
  float* mw0      = (float*)(ws + 128 + 4 * 8192);
  float* mw1      = (float*)(ws + 128 + 5 * 8192);
  int*   list_tok = (int*)(ws + 128 + 6 * 8192);
  ushort* act_buf = (ushort*)(ws + 65792);                                  // (4096+64) x 4096 bf16 = 34.1 MB
  float*  oe      = (float*)(ws + 65792 + (size_t)(2 * S + BM) * HF * 2);   // 4096 x 1024 f32 = 16.8 MB

  hipMemsetAsync(d_ws, 0, 64, stream);  // counts + cursor
  gate_kernel<<<S, 64, 0, stream>>>(x, gw, gb, counts, mi0, mi1, mw0, mw1);
  scan_kernel<<<1, 64, 0, stream>>>(counts, basep);
  fill_kernel<<<S / 256, 256, 0, stream>>>(mi0, mi1, cursor, basep, list_tok, mr0, mr1);
  gemm1_kernel<<<dim3(HF / BN, 256), 256, 0, stream>>>(x, w1, b1, counts, basep, list_tok, act_buf);
  gemm2_kernel<<<dim3(D / BN, 256), 256, 0, stream>>>(act_buf, w2, counts, basep, oe);
  combine_kernel<<<S, 256, 0, stream>>>(oe, mr0, mr1, mw0, mw1, mi0, mi1, b2, out);
}

// Round 2
// 414.074 us; speedup vs baseline: 1.2743x; 1.2743x over previous
//
#include <hip/hip_runtime.h>
#include <hip/hip_bf16.h>

#define S 2048
#define D 1024
#define NE 8
#define HF 4096
#define HH 8192
#define BK 32
#define ACT_ROWS 4224  // 4096 + 128 pad

typedef __attribute__((ext_vector_type(8))) __bf16 bf16x8;
typedef __attribute__((ext_vector_type(4))) float f32x4;

__device__ __forceinline__ unsigned bf16b(float f) {
  unsigned b = __float_as_uint(f);
  return (b + 0x7fffu + ((b >> 16) & 1u)) >> 16;  // RNE fp32->bf16 (finite)
}
__device__ __forceinline__ unsigned pk2(float lo, float hi) {
  return bf16b(lo) | (bf16b(hi) << 16);
}
__device__ __forceinline__ void gll16(const ushort* g, ushort* l) {
  __builtin_amdgcn_global_load_lds(
      (const __attribute__((address_space(1))) void*)g,
      (__attribute__((address_space(3))) void*)l, 16, 0, 0);
}

// ---------------- x: fp32 -> bf16 (layout unchanged, A-operand friendly) ----------------
__global__ __launch_bounds__(256) void convert_x(const float* __restrict__ x,
                                                 ushort* __restrict__ xb) {
  const int idx = blockIdx.x * 256 + threadIdx.x;  // 8 floats per thread
  const float4* src = (const float4*)x;
  float4 a = src[idx * 2], b = src[idx * 2 + 1];
  uint4 w = {pk2(a.x, a.y), pk2(a.z, a.w), pk2(b.x, b.y), pk2(b.z, b.w)};
  ((uint4*)xb)[idx] = w;
}

// ------------- W: [E][R][C] fp32 -> [E][C][R] bf16 (transpose + convert) -------------
__global__ __launch_bounds__(256) void transpose_convert(const float* __restrict__ src,
                                                         ushort* __restrict__ dst,
                                                         int R, int C) {
  const int e = blockIdx.z;
  const int n0 = blockIdx.x * 64;
  const int k0 = blockIdx.y * 64;
  const float* Sp = src + (size_t)e * R * C;
  ushort* Dp = dst + (size_t)e * R * C;
  __shared__ unsigned T[64][33];
  const int t = threadIdx.x;
  const int kp = t >> 4;         // 0..15
  const int nn = (t & 15) * 4;   // 0..60
#pragma unroll
  for (int j = 0; j < 2; ++j) {
    const int ka = k0 + 2 * kp + 32 * j;
    float4 a = *(const float4*)(Sp + (size_t)ka * C + n0 + nn);
    float4 b = *(const float4*)(Sp + (size_t)(ka + 1) * C + n0 + nn);
    T[nn + 0][kp + 16 * j] = pk2(a.x, b.x);
    T[nn + 1][kp + 16 * j] = pk2(a.y, b.y);
    T[nn + 2][kp + 16 * j] = pk2(a.z, b.z);
    T[nn + 3][kp + 16 * j] = pk2(a.w, b.w);
  }
  __syncthreads();
  const int n = t >> 2;
  const int kq = (t & 3) * 8;
  uint4 v0 = *(const uint4*)&T[n][kq];
  uint4 v1 = *(const uint4*)&T[n][kq + 4];
  uint4* out = (uint4*)(Dp + (size_t)(n0 + n) * R + k0 + kq * 2);
  out[0] = v0;
  out[1] = v1;
}

// ---------------- gating ----------------
__global__ void gate_kernel(const float* __restrict__ x, const float* __restrict__ gw,
                            const float* __restrict__ gb, int* __restrict__ counts,
                            int* __restrict__ mi0, int* __restrict__ mi1,
                            float* __restrict__ mw0, float* __restrict__ mw1) {
  const int t = blockIdx.x;
  const int l = threadIdx.x;
  const float* xr = x + (size_t)t * D;
  float acc[NE];
#pragma unroll
  for (int e = 0; e < NE; ++e) acc[e] = 0.f;
  for (int d = l; d < D; d += 64) {
    float xv = xr[d];
    const float* g = gw + (size_t)d * NE;
#pragma unroll
    for (int e = 0; e < NE; ++e) acc[e] += xv * g[e];
  }
#pragma unroll
  for (int e = 0; e < NE; ++e) {
    float v = acc[e];
#pragma unroll
    for (int off = 32; off > 0; off >>= 1) v += __shfl_xor(v, off);
    acc[e] = v;
  }
  if (l == 0) {
    float lg[NE];
#pragma unroll
    for (int e = 0; e < NE; ++e) lg[e] = acc[e] + gb[e];
    int i0 = 0; float m0 = lg[0];
#pragma unroll
    for (int e = 1; e < NE; ++e) if (lg[e] > m0) { m0 = lg[e]; i0 = e; }
    int i1 = -1; float m1 = -3.4e38f;
#pragma unroll
    for (int e = 0; e < NE; ++e) if (e != i0 && lg[e] > m1) { m1 = lg[e]; i1 = e; }
    float p = __expf(m1 - m0);
    float inv = 1.f / (1.f + p);
    mi0[t] = i0; mi1[t] = i1;
    mw0[t] = inv; mw1[t] = p * inv;
    atomicAdd(&counts[i0], 1);
    atomicAdd(&counts[i1], 1);
  }
}

__global__ void scan_kernel(const int* __restrict__ counts, int* __restrict__ basep) {
  if (threadIdx.x == 0) {
    int s = 0;
#pragma unroll
    for (int e = 0; e < NE; ++e) { basep[e] = s; s += counts[e]; }
    basep[NE] = s;
  }
}

__global__ void fill_kernel(const int* __restrict__ mi0, const int* __restrict__ mi1,
                            int* __restrict__ cursor, const int* __restrict__ basep,
                            int* __restrict__ list_tok, int* __restrict__ mr0,
                            int* __restrict__ mr1) {
  int t = blockIdx.x * blockDim.x + threadIdx.x;
  if (t >= S) return;
  int e0 = mi0[t];
  int r0 = basep[e0] + atomicAdd(&cursor[e0], 1);
  list_tok[r0] = t; mr0[t] = r0;
  int e1 = mi1[t];
  int r1 = basep[e1] + atomicAdd(&cursor[e1], 1);
  list_tok[r1] = t; mr1[t] = r1;
}

// -------- GEMM1 + SwiGLU: 128 rows x 64 act-cols (both H halves), bf16 all-MFMA --------
__global__ __launch_bounds__(256) void gemm1_kernel(
    const ushort* __restrict__ xb, const ushort* __restrict__ w1t,
    const float* __restrict__ b1, const int* __restrict__ counts,
    const int* __restrict__ basep, const int* __restrict__ list_tok,
    ushort* __restrict__ act_buf) {
  const int e = blockIdx.y >> 4;
  const int row0 = (blockIdx.y & 15) * 128;
  const int cnt = counts[e];
  if (row0 >= cnt) return;
  const int jt = blockIdx.x * 64;
  const ushort* __restrict__ W = w1t + (size_t)e * D * HH;  // [n=8192][k=1024] bf16
  const int gbase = basep[e];

  __shared__ ushort As[2][128][BK];
  __shared__ ushort Bs[2][128][BK];  // rows 0..63: x-half col jt+n ; 64..127: gate-half

  const int tid = threadIdx.x;
  const int w = tid >> 6;
  const int i = tid & 63;

  // staging: per-lane source pointers (row gather for A, half-split for B)
  const int rA0 = w * 32 + (i >> 2);
  const int rA1 = rA0 + 16;
  int s0 = row0 + rA0; if (s0 >= cnt) s0 = cnt - 1;
  int s1 = row0 + rA1; if (s1 >= cnt) s1 = cnt - 1;
  const ushort* pa0 = xb + (size_t)list_tok[gbase + s0] * D + (i & 3) * 8;
  const ushort* pa1 = xb + (size_t)list_tok[gbase + s1] * D + (i & 3) * 8;
  const ushort* pb0 = W + ((size_t)(rA0 >> 6) * HF + jt + (rA0 & 63)) * D + (i & 3) * 8;
  const ushort* pb1 = W + ((size_t)(rA1 >> 6) * HF + jt + (rA1 & 63)) * D + (i & 3) * 8;

  const int wm = (w >> 1) * 64;
  const int wn = (w & 1) * 32;
  const int lr = i & 15;
  const int kg = i >> 4;

  f32x4 acc[2][4][2] = {};  // [half][mi][ni]

  gll16(pa0, &As[0][w * 32][0]);
  gll16(pa1, &As[0][w * 32 + 16][0]);
  gll16(pb0, &Bs[0][w * 32][0]);
  gll16(pb1, &Bs[0][w * 32 + 16][0]);
  __syncthreads();

  int cur = 0;
#pragma unroll 1
  for (int it = 0; it < D / BK; ++it) {
    if (it + 1 < D / BK) {
      const int ko = (it + 1) * BK;
      gll16(pa0 + ko, &As[cur ^ 1][w * 32][0]);
      gll16(pa1 + ko, &As[cur ^ 1][w * 32 + 16][0]);
      gll16(pb0 + ko, &Bs[cur ^ 1][w * 32][0]);
      gll16(pb1 + ko, &Bs[cur ^ 1][w * 32 + 16][0]);
    }
    bf16x8 af[4], bfr[2][2];
#pragma unroll
    for (int mi = 0; mi < 4; ++mi)
      af[mi] = *(const bf16x8*)&As[cur][wm + mi * 16 + lr][kg * 8];
#pragma unroll
    for (int h = 0; h < 2; ++h)
#pragma unroll
      for (int ni = 0; ni < 2; ++ni)
        bfr[h][ni] = *(const bf16x8*)&Bs[cur][h * 64 + wn + ni * 16 + lr][kg * 8];
#pragma unroll
    for (int h = 0; h < 2; ++h)
#pragma unroll
      for (int mi = 0; mi < 4; ++mi)
#pragma unroll
        for (int ni = 0; ni < 2; ++ni)
          acc[h][mi][ni] = __builtin_amdgcn_mfma_f32_16x16x32_bf16(af[mi], bfr[h][ni],
                                                                   acc[h][mi][ni], 0, 0, 0);
    __syncthreads();
    cur ^= 1;
  }

#pragma unroll
  for (int mi = 0; mi < 4; ++mi)
#pragma unroll
    for (int ni = 0; ni < 2; ++ni) {
      const int c = jt + wn + ni * 16 + lr;
      const float bx = b1[(size_t)e * HH + c];
      const float bg = b1[(size_t)e * HH + HF + c];
      f32x4 vx = acc[0][mi][ni];
      f32x4 vg = acc[1][mi][ni];
#pragma unroll
      for (int q = 0; q < 4; ++q) {
        const int slot = row0 + wm + mi * 16 + kg * 4 + q;
        if (slot < cnt) {
          float xv = vx[q] + bx;
          float g = vg[q] + bg;
          float a = g / (1.f + __expf(-g)) * xv;
          act_buf[(size_t)(gbase + slot) * HF + c] = (ushort)bf16b(a);
        }
      }
    }
}

// -------------------- GEMM2 (K-split 2): oe[split] = act @ W2[e] --------------------
__global__ __launch_bounds__(256) void gemm2_kernel(
    const ushort* __restrict__ act_buf, const ushort* __restrict__ w2t,
    const int* __restrict__ counts, const int* __restrict__ basep,
    float* __restrict__ oe) {
  const int e = blockIdx.y >> 4;
  const int row0 = (blockIdx.y & 15) * 128;
  const int cnt = counts[e];
  if (row0 >= cnt) return;
  const int split = blockIdx.z;
  const int jt = blockIdx.x * 128;
  const ushort* __restrict__ W = w2t + (size_t)e * HF * D;  // [n=1024][kf=4096] bf16
  const int gbase = basep[e];

  __shared__ ushort As[2][128][BK];
  __shared__ ushort Bs[2][128][BK];

  const int tid = threadIdx.x;
  const int w = tid >> 6;
  const int i = tid & 63;

  const int r0 = w * 32 + (i >> 2);
  const size_t kbase = (size_t)split * (HF / 2);
  const ushort* pa0 = act_buf + (size_t)(gbase + row0 + r0) * HF + kbase + (i & 3) * 8;
  const ushort* pa1 = pa0 + (size_t)16 * HF;
  const ushort* pb0 = W + (size_t)(jt + r0) * HF + kbase + (i & 3) * 8;
  const ushort* pb1 = pb0 + (size_t)16 * HF;

  const int wm = (w >> 1) * 64;
  const int wn = (w & 1) * 64;
  const int lr = i & 15;
  const int kg = i >> 4;

  f32x4 acc[4][4] = {};

  gll16(pa0, &As[0][w * 32][0]);
  gll16(pa1, &As[0][w * 32 + 16][0]);
  gll16(pb0, &Bs[0][w * 32][0]);
  gll16(pb1, &Bs[0][w * 32 + 16][0]);
  __syncthreads();

  int cur = 0;
#pragma unroll 1
  for (int it = 0; it < (HF / 2) / BK; ++it) {
    if (it + 1 < (HF / 2) / BK) {
      const int ko = (it + 1) * BK;
      gll16(pa0 + ko, &As[cur ^ 1][w * 32][0]);
      gll16(pa1 + ko, &As[cur ^ 1][w * 32 + 16][0]);
      gll16(pb0 + ko, &Bs[cur ^ 1][w * 32][0]);
      gll16(pb1 + ko, &Bs[cur ^ 1][w * 32 + 16][0]);
    }
    bf16x8 af[4], bfr[4];
#pragma unroll
    for (int mi = 0; mi < 4; ++mi)
      af[mi] = *(const bf16x8*)&As[cur][wm + mi * 16 + lr][kg * 8];
#pragma unroll
    for (int ni = 0; ni < 4; ++ni)
      bfr[ni] = *(const bf16x8*)&Bs[cur][wn + ni * 16 + lr][kg * 8];
#pragma unroll
    for (int mi = 0; mi < 4; ++mi)
#pragma unroll
      for (int ni = 0; ni < 4; ++ni)
        acc[mi][ni] = __builtin_amdgcn_mfma_f32_16x16x32_bf16(af[mi], bfr[ni],
                                                              acc[mi][ni], 0, 0, 0);
    __syncthreads();
    cur ^= 1;
  }

#pragma unroll
  for (int mi = 0; mi < 4; ++mi)
#pragma unroll
    for (int ni = 0; ni < 4; ++ni) {
      f32x4 v = acc[mi][ni];
#pragma unroll
      for (int q = 0; q < 4; ++q) {
        const int slot = row0 + wm + mi * 16 + kg * 4 + q;
        if (slot < cnt)
          oe[((size_t)split * ACT_ROWS + gbase + slot) * D + jt + wn + ni * 16 + lr] = v[q];
      }
    }
}

// ---------------- combine: out[t] = w0*(oe0[r0]+oe1[r0]+b2[e0]) + w1*(...) ----------------
__global__ void combine_kernel(const float* __restrict__ oe,
                               const int* __restrict__ mr0, const int* __restrict__ mr1,
                               const float* __restrict__ mw0, const float* __restrict__ mw1,
                               const int* __restrict__ mi0, const int* __restrict__ mi1,
                               const float* __restrict__ b2, float* __restrict__ out) {
  const int t = blockIdx.x;
  const int l = threadIdx.x;
  const float w0 = mw0[t], w1 = mw1[t];
  const float4* p00 = (const float4*)(oe + (size_t)mr0[t] * D);
  const float4* p01 = (const float4*)(oe + ((size_t)ACT_ROWS + mr0[t]) * D);
  const float4* p10 = (const float4*)(oe + (size_t)mr1[t] * D);
  const float4* p11 = (const float4*)(oe + ((size_t)ACT_ROWS + mr1[t]) * D);
  const float4* c0 = (const float4*)(b2 + (size_t)mi0[t] * D);
  const float4* c1 = (const float4*)(b2 + (size_t)mi1[t] * D);
  float4 A0 = p00[l], A1 = p01[l], B0 = p10[l], B1 = p11[l], C = c0[l], E2 = c1[l];
  float4 r;
  r.x = w0 * (A0.x + A1.x + C.x) + w1 * (B0.x + B1.x + E2.x);
  r.y = w0 * (A0.y + A1.y + C.y) + w1 * (B0.y + B1.y + E2.y);
  r.z = w0 * (A0.z + A1.z + C.z) + w1 * (B0.z + B1.z + E2.z);
  r.w = w0 * (A0.w + A1.w + C.w) + w1 * (B0.w + B1.w + E2.w);
  ((float4*)(out + (size_t)t * D))[l] = r;
}

extern "C" void kernel_launch(void* const* d_in, const int* in_sizes, int n_in,
                              void* d_out, int out_size, void* d_ws, size_t ws_size,
                              hipStream_t stream) {
  const float* x  = (const float*)d_in[0];
  const float* gw = (const float*)d_in[1];
  const float* gb = (const float*)d_in[2];
  const float* w1 = (const float*)d_in[3];
  const float* b1 = (const float*)d_in[4];
  const float* w2 = (const float*)d_in[5];
  const float* b2 = (const float*)d_in[6];
  float* out = (float*)d_out;

  char* ws = (char*)d_ws;
  int*   counts   = (int*)(ws + 0);
  int*   cursor   = (int*)(ws + 32);
  int*   basep    = (int*)(ws + 64);
  int*   mi0      = (int*)(ws + 128);
  int*   mi1      = (int*)(ws + 128 + 1 * 8192);
  int*   mr0      = (int*)(ws + 128 + 2 * 8192);
  int*   mr1      = (int*)(ws + 128 + 3 * 8192);
  float* mw0      = (float*)(ws + 128 + 4 * 8192);
  float* mw1      = (float*)(ws + 128 + 5 * 8192);
  int*   list_tok = (int*)(ws + 128 + 6 * 8192);
  ushort* xb      = (ushort*)(ws + 65792);                  // 4 MB
  ushort* act_buf = (ushort*)(ws + 4260096);                // 34.6 MB (4224 x 4096 bf16)
  float*  oe      = (float*)(ws + 38863104);                // 34.6 MB (2 x 4224 x 1024 f32)
  ushort* w1t     = (ushort*)(ws + 73466112);               // 134 MB
  ushort* w2t     = (ushort*)(ws + 207683840);              // 67 MB (end: 274.8 MB)

  hipMemsetAsync(d_ws, 0, 64, stream);  // counts + cursor
  convert_x<<<(S * D) / (256 * 8), 256, 0, stream>>>(x, xb);
  transpose_convert<<<dim3(HH / 64, D / 64, NE), 256, 0, stream>>>(w1, w1t, D, HH);
  transpose_convert<<<dim3(D / 64, HF / 64, NE), 256, 0, stream>>>(w2, w2t, HF, D);
  gate_kernel<<<S, 64, 0, stream>>>(x, gw, gb, counts, mi0, mi1, mw0, mw1);
  scan_kernel<<<1, 64, 0, stream>>>(counts, basep);
  fill_kernel<<<S / 256, 256, 0, stream>>>(mi0, mi1, cursor, basep, list_tok, mr0, mr1);
  gemm1_kernel<<<dim3(HF / 64, NE * 16), 256, 0, stream>>>(xb, w1t, b1, counts, basep,
                                                           list_tok, act_buf);
  gemm2_kernel<<<dim3(D / 128, NE * 16, 2), 256, 0, stream>>>(act_buf, w2t, counts, basep, oe);
  combine_kernel<<<S, 256, 0, stream>>>(oe, mr0, mr1, mw0, mw1, mi0, mi1, b2, out);
}

// Round 3
// 342.848 us; speedup vs baseline: 1.5391x; 1.2077x over previous
//
#include <hip/hip_runtime.h>
#include <hip/hip_bf16.h>

#define S 2048
#define D 1024
#define NE 8
#define HF 4096
#define HH 8192
#define BK 32
#define ACT_ROWS 4224  // 4096 + 128 pad

typedef __attribute__((ext_vector_type(8))) __bf16 bf16x8;
typedef __attribute__((ext_vector_type(4))) float f32x4;

__device__ __forceinline__ unsigned bf16b(float f) {
  unsigned b = __float_as_uint(f);
  return (b + 0x7fffu + ((b >> 16) & 1u)) >> 16;  // RNE fp32->bf16 (finite)
}
__device__ __forceinline__ unsigned pk2(float lo, float hi) {
  return bf16b(lo) | (bf16b(hi) << 16);
}
__device__ __forceinline__ void gll16(const ushort* g, ushort* l) {
  __builtin_amdgcn_global_load_lds(
      (const __attribute__((address_space(1))) void*)g,
      (__attribute__((address_space(3))) void*)l, 16, 0, 0);
}

// ---------------- x: fp32 -> bf16 (layout unchanged, A-operand friendly) ----------------
__global__ __launch_bounds__(256) void convert_x(const float* __restrict__ x,
                                                 ushort* __restrict__ xb) {
  const int idx = blockIdx.x * 256 + threadIdx.x;  // 8 floats per thread
  const float4* src = (const float4*)x;
  float4 a = src[idx * 2], b = src[idx * 2 + 1];
  uint4 w = {pk2(a.x, a.y), pk2(a.z, a.w), pk2(b.x, b.y), pk2(b.z, b.w)};
  ((uint4*)xb)[idx] = w;
}

// ------------- W: [E][R][C] fp32 -> [E][C][R] bf16 (transpose + convert) -------------
__global__ __launch_bounds__(256) void transpose_convert(const float* __restrict__ src,
                                                         ushort* __restrict__ dst,
                                                         int R, int C) {
  const int e = blockIdx.z;
  const int n0 = blockIdx.x * 64;
  const int k0 = blockIdx.y * 64;
  const float* Sp = src + (size_t)e * R * C;
  ushort* Dp = dst + (size_t)e * R * C;
  __shared__ unsigned T[64][33];
  const int t = threadIdx.x;
  const int kp = t >> 4;         // 0..15
  const int nn = (t & 15) * 4;   // 0..60
#pragma unroll
  for (int j = 0; j < 2; ++j) {
    const int ka = k0 + 2 * kp + 32 * j;
    float4 a = *(const float4*)(Sp + (size_t)ka * C + n0 + nn);
    float4 b = *(const float4*)(Sp + (size_t)(ka + 1) * C + n0 + nn);
    T[nn + 0][kp + 16 * j] = pk2(a.x, b.x);
    T[nn + 1][kp + 16 * j] = pk2(a.y, b.y);
    T[nn + 2][kp + 16 * j] = pk2(a.z, b.z);
    T[nn + 3][kp + 16 * j] = pk2(a.w, b.w);
  }
  __syncthreads();
  const int n = t >> 2;
  const int kq = (t & 3) * 8;
  uint4 v0 = *(const uint4*)&T[n][kq];
  uint4 v1 = *(const uint4*)&T[n][kq + 4];
  uint4* out = (uint4*)(Dp + (size_t)(n0 + n) * R + k0 + kq * 2);
  out[0] = v0;
  out[1] = v1;
}

// ---------------- gating (no global atomics) ----------------
__global__ void gate_kernel(const float* __restrict__ x, const float* __restrict__ gw,
                            const float* __restrict__ gb,
                            int* __restrict__ mi0, int* __restrict__ mi1,
                            float* __restrict__ mw0, float* __restrict__ mw1) {
  const int t = blockIdx.x;
  const int l = threadIdx.x;
  const float* xr = x + (size_t)t * D;
  float acc[NE];
#pragma unroll
  for (int e = 0; e < NE; ++e) acc[e] = 0.f;
  for (int d = l; d < D; d += 64) {
    float xv = xr[d];
    const float* g = gw + (size_t)d * NE;
#pragma unroll
    for (int e = 0; e < NE; ++e) acc[e] += xv * g[e];
  }
#pragma unroll
  for (int e = 0; e < NE; ++e) {
    float v = acc[e];
#pragma unroll
    for (int off = 32; off > 0; off >>= 1) v += __shfl_xor(v, off);
    acc[e] = v;
  }
  if (l == 0) {
    float lg[NE];
#pragma unroll
    for (int e = 0; e < NE; ++e) lg[e] = acc[e] + gb[e];
    int i0 = 0; float m0 = lg[0];
#pragma unroll
    for (int e = 1; e < NE; ++e) if (lg[e] > m0) { m0 = lg[e]; i0 = e; }  // strict >: first idx on ties (jax)
    int i1 = -1; float m1 = -3.4e38f;
#pragma unroll
    for (int e = 0; e < NE; ++e) if (e != i0 && lg[e] > m1) { m1 = lg[e]; i1 = e; }
    float p = __expf(m1 - m0);
    float inv = 1.f / (1.f + p);
    mi0[t] = i0; mi1[t] = i1;
    mw0[t] = inv; mw1[t] = p * inv;
  }
}

// ------------- routing: counts + prefix + slot assignment, one block -------------
__global__ __launch_bounds__(1024) void route_kernel(
    const int* __restrict__ mi0, const int* __restrict__ mi1,
    int* __restrict__ counts, int* __restrict__ basep, int* __restrict__ list_tok,
    int* __restrict__ mr0, int* __restrict__ mr1) {
  __shared__ int cnt[NE];
  __shared__ int cur[NE];
  const int t = threadIdx.x;
  if (t < NE) cnt[t] = 0;
  __syncthreads();
  const int e0a = mi0[t], e1a = mi1[t];
  const int e0b = mi0[t + 1024], e1b = mi1[t + 1024];
  atomicAdd(&cnt[e0a], 1); atomicAdd(&cnt[e1a], 1);
  atomicAdd(&cnt[e0b], 1); atomicAdd(&cnt[e1b], 1);
  __syncthreads();
  if (t == 0) {
    int s = 0;
#pragma unroll
    for (int e = 0; e < NE; ++e) { basep[e] = s; cur[e] = s; s += cnt[e]; }
    basep[NE] = s;
  }
  if (t < NE) counts[t] = cnt[t];
  __syncthreads();
  int r;
  r = atomicAdd(&cur[e0a], 1); list_tok[r] = t; mr0[t] = r;
  r = atomicAdd(&cur[e1a], 1); list_tok[r] = t; mr1[t] = r;
  r = atomicAdd(&cur[e0b], 1); list_tok[r] = t + 1024; mr0[t + 1024] = r;
  r = atomicAdd(&cur[e1b], 1); list_tok[r] = t + 1024; mr1[t + 1024] = r;
}

// -------- GEMM1 + SwiGLU: 128 rows x 64 act-cols (both H halves), bf16 all-MFMA --------
__global__ __launch_bounds__(256) void gemm1_kernel(
    const ushort* __restrict__ xb, const ushort* __restrict__ w1t,
    const float* __restrict__ b1, const int* __restrict__ counts,
    const int* __restrict__ basep, const int* __restrict__ list_tok,
    ushort* __restrict__ act_buf) {
  const int e = blockIdx.y >> 4;
  const int row0 = (blockIdx.y & 15) * 128;
  const int cnt = counts[e];
  if (row0 >= cnt) return;
  const int jt = blockIdx.x * 64;
  const ushort* __restrict__ W = w1t + (size_t)e * D * HH;  // [n=8192][k=1024] bf16
  const int gbase = basep[e];

  __shared__ ushort As[2][128][BK];
  __shared__ ushort Bs[2][128][BK];  // rows 0..63: x-half col jt+n ; 64..127: gate-half

  const int tid = threadIdx.x;
  const int w = tid >> 6;
  const int i = tid & 63;

  const int rA0 = w * 32 + (i >> 2);
  const int rA1 = rA0 + 16;
  int s0 = row0 + rA0; if (s0 >= cnt) s0 = cnt - 1;
  int s1 = row0 + rA1; if (s1 >= cnt) s1 = cnt - 1;
  const ushort* pa0 = xb + (size_t)list_tok[gbase + s0] * D + (i & 3) * 8;
  const ushort* pa1 = xb + (size_t)list_tok[gbase + s1] * D + (i & 3) * 8;
  const ushort* pb0 = W + ((size_t)(rA0 >> 6) * HF + jt + (rA0 & 63)) * D + (i & 3) * 8;
  const ushort* pb1 = W + ((size_t)(rA1 >> 6) * HF + jt + (rA1 & 63)) * D + (i & 3) * 8;

  const int wm = (w >> 1) * 64;
  const int wn = (w & 1) * 32;
  const int lr = i & 15;
  const int kg = i >> 4;

  f32x4 acc[2][4][2] = {};  // [half][mi][ni]

  gll16(pa0, &As[0][w * 32][0]);
  gll16(pa1, &As[0][w * 32 + 16][0]);
  gll16(pb0, &Bs[0][w * 32][0]);
  gll16(pb1, &Bs[0][w * 32 + 16][0]);
  __syncthreads();

  int cur = 0;
#pragma unroll 1
  for (int it = 0; it < D / BK; ++it) {
    if (it + 1 < D / BK) {
      const int ko = (it + 1) * BK;
      gll16(pa0 + ko, &As[cur ^ 1][w * 32][0]);
      gll16(pa1 + ko, &As[cur ^ 1][w * 32 + 16][0]);
      gll16(pb0 + ko, &Bs[cur ^ 1][w * 32][0]);
      gll16(pb1 + ko, &Bs[cur ^ 1][w * 32 + 16][0]);
    }
    bf16x8 af[4], bfr[2][2];
#pragma unroll
    for (int mi = 0; mi < 4; ++mi)
      af[mi] = *(const bf16x8*)&As[cur][wm + mi * 16 + lr][kg * 8];
#pragma unroll
    for (int h = 0; h < 2; ++h)
#pragma unroll
      for (int ni = 0; ni < 2; ++ni)
        bfr[h][ni] = *(const bf16x8*)&Bs[cur][h * 64 + wn + ni * 16 + lr][kg * 8];
#pragma unroll
    for (int h = 0; h < 2; ++h)
#pragma unroll
      for (int mi = 0; mi < 4; ++mi)
#pragma unroll
        for (int ni = 0; ni < 2; ++ni)
          acc[h][mi][ni] = __builtin_amdgcn_mfma_f32_16x16x32_bf16(af[mi], bfr[h][ni],
                                                                   acc[h][mi][ni], 0, 0, 0);
    __syncthreads();
    cur ^= 1;
  }

#pragma unroll
  for (int mi = 0; mi < 4; ++mi)
#pragma unroll
    for (int ni = 0; ni < 2; ++ni) {
      const int c = jt + wn + ni * 16 + lr;
      const float bx = b1[(size_t)e * HH + c];
      const float bg = b1[(size_t)e * HH + HF + c];
      f32x4 vx = acc[0][mi][ni];
      f32x4 vg = acc[1][mi][ni];
#pragma unroll
      for (int q = 0; q < 4; ++q) {
        const int slot = row0 + wm + mi * 16 + kg * 4 + q;
        if (slot < cnt) {
          float xv = vx[q] + bx;
          float g = vg[q] + bg;
          float a = g / (1.f + __expf(-g)) * xv;
          act_buf[(size_t)(gbase + slot) * HF + c] = (ushort)bf16b(a);
        }
      }
    }
}

// -------------------- GEMM2 (K-split 2): oe[split] = act @ W2[e] --------------------
__global__ __launch_bounds__(256) void gemm2_kernel(
    const ushort* __restrict__ act_buf, const ushort* __restrict__ w2t,
    const int* __restrict__ counts, const int* __restrict__ basep,
    float* __restrict__ oe) {
  const int e = blockIdx.y >> 4;
  const int row0 = (blockIdx.y & 15) * 128;
  const int cnt = counts[e];
  if (row0 >= cnt) return;
  const int split = blockIdx.z;
  const int jt = blockIdx.x * 128;
  const ushort* __restrict__ W = w2t + (size_t)e * HF * D;  // [n=1024][kf=4096] bf16
  const int gbase = basep[e];

  __shared__ ushort As[2][128][BK];
  __shared__ ushort Bs[2][128][BK];

  const int tid = threadIdx.x;
  const int w = tid >> 6;
  const int i = tid & 63;

  const int r0 = w * 32 + (i >> 2);
  const size_t kbase = (size_t)split * (HF / 2);
  const ushort* pa0 = act_buf + (size_t)(gbase + row0 + r0) * HF + kbase + (i & 3) * 8;
  const ushort* pa1 = pa0 + (size_t)16 * HF;
  const ushort* pb0 = W + (size_t)(jt + r0) * HF + kbase + (i & 3) * 8;
  const ushort* pb1 = pb0 + (size_t)16 * HF;

  const int wm = (w >> 1) * 64;
  const int wn = (w & 1) * 64;
  const int lr = i & 15;
  const int kg = i >> 4;

  f32x4 acc[4][4] = {};

  gll16(pa0, &As[0][w * 32][0]);
  gll16(pa1, &As[0][w * 32 + 16][0]);
  gll16(pb0, &Bs[0][w * 32][0]);
  gll16(pb1, &Bs[0][w * 32 + 16][0]);
  __syncthreads();

  int cur = 0;
#pragma unroll 1
  for (int it = 0; it < (HF / 2) / BK; ++it) {
    if (it + 1 < (HF / 2) / BK) {
      const int ko = (it + 1) * BK;
      gll16(pa0 + ko, &As[cur ^ 1][w * 32][0]);
      gll16(pa1 + ko, &As[cur ^ 1][w * 32 + 16][0]);
      gll16(pb0 + ko, &Bs[cur ^ 1][w * 32][0]);
      gll16(pb1 + ko, &Bs[cur ^ 1][w * 32 + 16][0]);
    }
    bf16x8 af[4], bfr[4];
#pragma unroll
    for (int mi = 0; mi < 4; ++mi)
      af[mi] = *(const bf16x8*)&As[cur][wm + mi * 16 + lr][kg * 8];
#pragma unroll
    for (int ni = 0; ni < 4; ++ni)
      bfr[ni] = *(const bf16x8*)&Bs[cur][wn + ni * 16 + lr][kg * 8];
#pragma unroll
    for (int mi = 0; mi < 4; ++mi)
#pragma unroll
      for (int ni = 0; ni < 4; ++ni)
        acc[mi][ni] = __builtin_amdgcn_mfma_f32_16x16x32_bf16(af[mi], bfr[ni],
                                                              acc[mi][ni], 0, 0, 0);
    __syncthreads();
    cur ^= 1;
  }

#pragma unroll
  for (int mi = 0; mi < 4; ++mi)
#pragma unroll
    for (int ni = 0; ni < 4; ++ni) {
      f32x4 v = acc[mi][ni];
#pragma unroll
      for (int q = 0; q < 4; ++q) {
        const int slot = row0 + wm + mi * 16 + kg * 4 + q;
        if (slot < cnt)
          oe[((size_t)split * ACT_ROWS + gbase + slot) * D + jt + wn + ni * 16 + lr] = v[q];
      }
    }
}

// ---------------- combine: out[t] = w0*(oe0[r0]+oe1[r0]+b2[e0]) + w1*(...) ----------------
__global__ void combine_kernel(const float* __restrict__ oe,
                               const int* __restrict__ mr0, const int* __restrict__ mr1,
                               const float* __restrict__ mw0, const float* __restrict__ mw1,
                               const int* __restrict__ mi0, const int* __restrict__ mi1,
                               const float* __restrict__ b2, float* __restrict__ out) {
  const int t = blockIdx.x;
  const int l = threadIdx.x;
  const float w0 = mw0[t], w1 = mw1[t];
  const float4* p00 = (const float4*)(oe + (size_t)mr0[t] * D);
  const float4* p01 = (const float4*)(oe + ((size_t)ACT_ROWS + mr0[t]) * D);
  const float4* p10 = (const float4*)(oe + (size_t)mr1[t] * D);
  const float4* p11 = (const float4*)(oe + ((size_t)ACT_ROWS + mr1[t]) * D);
  const float4* c0 = (const float4*)(b2 + (size_t)mi0[t] * D);
  const float4* c1 = (const float4*)(b2 + (size_t)mi1[t] * D);
  float4 A0 = p00[l], A1 = p01[l], B0 = p10[l], B1 = p11[l], C = c0[l], E2 = c1[l];
  float4 r;
  r.x = w0 * (A0.x + A1.x + C.x) + w1 * (B0.x + B1.x + E2.x);
  r.y = w0 * (A0.y + A1.y + C.y) + w1 * (B0.y + B1.y + E2.y);
  r.z = w0 * (A0.z + A1.z + C.z) + w1 * (B0.z + B1.z + E2.z);
  r.w = w0 * (A0.w + A1.w + C.w) + w1 * (B0.w + B1.w + E2.w);
  ((float4*)(out + (size_t)t * D))[l] = r;
}

extern "C" void kernel_launch(void* const* d_in, const int* in_sizes, int n_in,
                              void* d_out, int out_size, void* d_ws, size_t ws_size,
                              hipStream_t stream) {
  const float* x  = (const float*)d_in[0];
  const float* gw = (const float*)d_in[1];
  const float* gb = (const float*)d_in[2];
  const float* w1 = (const float*)d_in[3];
  const float* b1 = (const float*)d_in[4];
  const float* w2 = (const float*)d_in[5];
  const float* b2 = (const float*)d_in[6];
  float* out = (float*)d_out;

  char* ws = (char*)d_ws;
  int*   counts   = (int*)(ws + 0);
  int*   basep    = (int*)(ws + 64);
  int*   mi0      = (int*)(ws + 128);
  int*   mi1      = (int*)(ws + 128 + 1 * 8192);
  int*   mr0      = (int*)(ws + 128 + 2 * 8192);
  int*   mr1      = (int*)(ws + 128 + 3 * 8192);
  float* mw0      = (float*)(ws + 128 + 4 * 8192);
  float* mw1      = (float*)(ws + 128 + 5 * 8192);
  int*   list_tok = (int*)(ws + 128 + 6 * 8192);
  ushort* xb      = (ushort*)(ws + 65792);                  // 4 MB
  ushort* act_buf = (ushort*)(ws + 4260096);                // 34.6 MB (4224 x 4096 bf16)
  float*  oe      = (float*)(ws + 38863104);                // 34.6 MB (2 x 4224 x 1024 f32)
  ushort* w1t     = (ushort*)(ws + 73466112);               // 134 MB
  ushort* w2t     = (ushort*)(ws + 207683840);              // 67 MB (end: 274.8 MB)

  convert_x<<<(S * D) / (256 * 8), 256, 0, stream>>>(x, xb);
  transpose_convert<<<dim3(HH / 64, D / 64, NE), 256, 0, stream>>>(w1, w1t, D, HH);
  transpose_convert<<<dim3(D / 64, HF / 64, NE), 256, 0, stream>>>(w2, w2t, HF, D);
  gate_kernel<<<S, 64, 0, stream>>>(x, gw, gb, mi0, mi1, mw0, mw1);
  route_kernel<<<1, 1024, 0, stream>>>(mi0, mi1, counts, basep, list_tok, mr0, mr1);
  gemm1_kernel<<<dim3(HF / 64, NE * 16), 256, 0, stream>>>(xb, w1t, b1, counts, basep,
                                                           list_tok, act_buf);
  gemm2_kernel<<<dim3(D / 128, NE * 16, 2), 256, 0, stream>>>(act_buf, w2t, counts, basep, oe);
  combine_kernel<<<S, 256, 0, stream>>>(oe, mr0, mr1, mw0, mw1, mi0, mi1, b2, out);
}